// Round 1
// baseline (259.258 us; speedup 1.0000x reference)
//
#include <hip/hip_runtime.h>
#include <stdint.h>

// Problem constants
#define N_ROWS 32768
#define DIM    1024
#define HENC   512
#define NZ     64
#define KE     16
#define HEXP   256
#define NC     10

typedef __attribute__((ext_vector_type(8))) __bf16 bf16x8;
typedef __attribute__((ext_vector_type(4))) float f32x4;
typedef __attribute__((ext_vector_type(8))) unsigned short u16x8;
typedef __attribute__((ext_vector_type(4))) unsigned short u16x4;

__device__ __forceinline__ unsigned short f2bf(float f) {
    __bf16 h = (__bf16)f;  // RNE convert
    return __builtin_bit_cast(unsigned short, h);
}

// async global->LDS, 16B per lane. LDS dst must be wave-uniform (HW adds lane*16).
__device__ __forceinline__ void gload_lds16(void* lds, const void* gsrc) {
    __builtin_amdgcn_global_load_lds(
        (const __attribute__((address_space(1))) unsigned int*)gsrc,
        (__attribute__((address_space(3))) unsigned int*)lds,
        16, 0, 0);
}

// XOR swizzle in bf16-element space: flips 16B-granule bits 3..5 by row&7.
// Applied identically on write and read.
#define SWZ(col, row) ((col) ^ (((row) & 7) << 3))

// ---------------------------------------------------------------------------
// Kernel 0: cast+transpose all weights to bf16 so MFMA B-fragments are
// k-contiguous. enc_Wt [512][1024], z_Wt [64][512], W1t [16][256][64],
// W2t [16][16][256] (cols 10..15 zero-padded).
// ---------------------------------------------------------------------------
__global__ void prep_weights(const float* __restrict__ enc_W,
                             const float* __restrict__ z_W,
                             const float* __restrict__ W1,
                             const float* __restrict__ W2,
                             unsigned short* __restrict__ enc_Wt,
                             unsigned short* __restrict__ z_Wt,
                             unsigned short* __restrict__ W1t,
                             unsigned short* __restrict__ W2t) {
    int i = blockIdx.x * 256 + threadIdx.x;
    if (i < 524288) {                       // enc_Wt[n][k] = enc_W[k][n]
        int n = i >> 10, k = i & 1023;
        enc_Wt[i] = f2bf(enc_W[k * HENC + n]);
    } else if (i < 557056) {                // z_Wt[n][k] = z_W[k][n]
        int i2 = i - 524288;
        int n = i2 >> 9, k = i2 & 511;
        z_Wt[i2] = f2bf(z_W[k * NZ + n]);
    } else if (i < 819200) {                // W1t[e][h][d] = W1[e][d][h]
        int i3 = i - 557056;
        int e = i3 >> 14, rem = i3 & 16383;
        int h = rem >> 6, d = rem & 63;
        W1t[i3] = f2bf(W1[(e * NZ + d) * HEXP + h]);
    } else if (i < 884736) {                // W2t[e][c][h] = W2[e][h][c], pad c>=10
        int i4 = i - 819200;
        int e = i4 >> 12, rem = i4 & 4095;
        int c = rem >> 8, h = rem & 255;
        W2t[i4] = (c < NC) ? f2bf(W2[(e * HEXP + h) * NC + c]) : (unsigned short)0;
    }
}

// ---------------------------------------------------------------------------
// Fused encoder: z = (relu(X @ enc_W + enc_b)) @ z_W + z_b.
// One block = BM=64 rows x full N=512. 512 threads = 8 waves (2 row-groups x
// 4 col-groups), acc[2][8] per wave (64x128 hb chunk).
//  - X tile (64x64 f32 -> bf16) reg-staged into XOR-swizzled LDS, double-
//    buffered, next-step loads issued before MFMAs (T14 split).
//  - enc_Wt B-fragments read directly from global (1 MB, L2-resident) like
//    gemm2 did for zWt -- no B staging, no vmcnt(0) drain on B.
//  - After K1 loop: bias+relu -> hb tile (64x512 bf16) into swizzled LDS
//    (union over the X buffers), then 64x64 z-GEMM vs L2-resident zWt.
// hb never touches HBM (saves 67 MB traffic + one launch).
// ---------------------------------------------------------------------------
__launch_bounds__(512, 2)
__global__ void enc_fused(const float* __restrict__ X,
                          const unsigned short* __restrict__ encWt,  // [512][1024]
                          const float* __restrict__ enc_b,
                          const unsigned short* __restrict__ zWt,    // [64][512]
                          const float* __restrict__ z_b,
                          float* __restrict__ z) {
    __shared__ union LU {
        unsigned short Xs[2][64][64];    // 16 KB (double-buffered A tile)
        unsigned short hbs[64][512];     // 64 KB (hb tile for z-GEMM)
    } u;

    const int t = threadIdx.x;
    const int lane = t & 63;
    const int w = t >> 6;
    const int g = lane >> 4;
    const int l15 = lane & 15;
    const int wm = (w >> 2) * 32;        // row-group base (0 or 32)
    const int wn = (w & 3) * 128;        // col-group base (0..384)
    const int r0 = blockIdx.x * 64;

    // A staging: thread covers rows arow, arow+32; cols acolq*4 (f32)
    const int arow = t >> 4;             // 0..31
    const int acolq = t & 15;
    const float* aptr = X + (size_t)(r0 + arow) * DIM + acolq * 4;
    const int ascol = SWZ(acolq * 4, arow);   // (arow+32)&7 == arow&7

    f32x4 acc[2][8];
#pragma unroll
    for (int i = 0; i < 2; ++i)
#pragma unroll
        for (int j = 0; j < 8; ++j) acc[i][j] = f32x4{0.f, 0.f, 0.f, 0.f};

    // prologue: stage k-step 0
    {
        float4 a0 = *(const float4*)(aptr);
        float4 a1 = *(const float4*)(aptr + (size_t)32 * DIM);
        u16x4 p0, p1;
        p0[0] = f2bf(a0.x); p0[1] = f2bf(a0.y); p0[2] = f2bf(a0.z); p0[3] = f2bf(a0.w);
        p1[0] = f2bf(a1.x); p1[1] = f2bf(a1.y); p1[2] = f2bf(a1.z); p1[3] = f2bf(a1.w);
        *(u16x4*)&u.Xs[0][arow][ascol] = p0;
        *(u16x4*)&u.Xs[0][arow + 32][ascol] = p1;
    }
    __syncthreads();

    for (int step = 0; step < 16; ++step) {
        const int cur = step & 1, nxt = cur ^ 1;
        const int k0 = step * 64;

        // B fragments for this step (both kk halves), straight from L2
        bf16x8 b0[8], b1[8];
#pragma unroll
        for (int j = 0; j < 8; ++j) {
            const unsigned short* bp =
                encWt + (size_t)(wn + j * 16 + l15) * DIM + k0 + g * 8;
            b0[j] = *(const bf16x8*)bp;
            b1[j] = *(const bf16x8*)(bp + 32);
        }

        // issue next-step X loads now; consume after MFMAs (latency hidden)
        float4 a0n, a1n;
        if (step < 15) {
            a0n = *(const float4*)(aptr + k0 + 64);
            a1n = *(const float4*)(aptr + (size_t)32 * DIM + k0 + 64);
        }

        // compute: 2 kk halves x (2 row-frags x 8 col-frags)
#pragma unroll
        for (int kk = 0; kk < 2; ++kk) {
            const int sko = SWZ(kk * 32 + g * 8, l15 & 7);
            bf16x8 af0 = *(const bf16x8*)&u.Xs[cur][wm + l15][sko];
            bf16x8 af1 = *(const bf16x8*)&u.Xs[cur][wm + 16 + l15][sko];
#pragma unroll
            for (int j = 0; j < 8; ++j) {
                bf16x8 bw = kk ? b1[j] : b0[j];
                acc[0][j] = __builtin_amdgcn_mfma_f32_16x16x32_bf16(af0, bw, acc[0][j], 0, 0, 0);
                acc[1][j] = __builtin_amdgcn_mfma_f32_16x16x32_bf16(af1, bw, acc[1][j], 0, 0, 0);
            }
        }

        // write next buffer (WAR on Xs[nxt] protected by the step-end barrier)
        if (step < 15) {
            u16x4 p0, p1;
            p0[0] = f2bf(a0n.x); p0[1] = f2bf(a0n.y); p0[2] = f2bf(a0n.z); p0[3] = f2bf(a0n.w);
            p1[0] = f2bf(a1n.x); p1[1] = f2bf(a1n.y); p1[2] = f2bf(a1n.z); p1[3] = f2bf(a1n.w);
            *(u16x4*)&u.Xs[nxt][arow][ascol] = p0;
            *(u16x4*)&u.Xs[nxt][arow + 32][ascol] = p1;
        }
        __syncthreads();
    }

    // epilogue 1: hb = relu(acc + enc_b) -> swizzled LDS tile (overwrites Xs;
    // safe: barrier after last compute step already executed)
#pragma unroll
    for (int j = 0; j < 8; ++j) {
        const int col = wn + j * 16 + l15;
        const float bias = enc_b[col];
#pragma unroll
        for (int i = 0; i < 2; ++i) {
#pragma unroll
            for (int r = 0; r < 4; ++r) {
                const int row = wm + i * 16 + g * 4 + r;
                float v = acc[i][j][r] + bias;
                v = v > 0.f ? v : 0.f;
                u.hbs[row][SWZ(col, row)] = f2bf(v);
            }
        }
    }
    __syncthreads();

    // epilogue 2: z tile = hb @ z_W + z_b  (64 x 64, K=512)
    // wave w: rows (w&3)*16, cols (w>>2)*32
    {
        const int zrow = (w & 3) * 16 + l15;     // zrow&7 == l15&7
        const int zcol0 = (w >> 2) * 32;
        f32x4 zacc[2] = {f32x4{0.f, 0.f, 0.f, 0.f}, f32x4{0.f, 0.f, 0.f, 0.f}};
#pragma unroll
        for (int ks = 0; ks < 16; ++ks) {
            const int k = ks * 32 + g * 8;
            bf16x8 a = *(const bf16x8*)&u.hbs[zrow][SWZ(k, zrow)];
#pragma unroll
            for (int j = 0; j < 2; ++j) {
                bf16x8 b = *(const bf16x8*)(zWt + (size_t)(zcol0 + j * 16 + l15) * HENC + k);
                zacc[j] = __builtin_amdgcn_mfma_f32_16x16x32_bf16(a, b, zacc[j], 0, 0, 0);
            }
        }
#pragma unroll
        for (int j = 0; j < 2; ++j) {
            const int col = zcol0 + j * 16 + l15;
            const float zb = z_b[col];
#pragma unroll
            for (int r = 0; r < 4; ++r) {
                const int row = (w & 3) * 16 + g * 4 + r;
                z[(size_t)(r0 + row) * NZ + col] = zacc[j][r] + zb;
            }
        }
    }
}

// ---------------------------------------------------------------------------
// Kernel 3: fused q + experts + combine. 256 blocks (1/CU), 128 rows each.
// dist via MFMA (|z|^2 - 2 z@mu^T + |mu|^2), per-expert 64->256->10 MLP via
// MFMA with eh LDS round-trip, preds accumulated in registers.
// w1s/w2s XOR-swizzled (write and read) to kill fragment-read conflicts.
// ---------------------------------------------------------------------------
__launch_bounds__(256, 1)
__global__ void expert_kernel(const float* __restrict__ z,
                              const float* __restrict__ mu,
                              const unsigned short* __restrict__ W1t,  // [16][256][64]
                              const float* __restrict__ b1,
                              const unsigned short* __restrict__ W2t,  // [16][16][256]
                              const float* __restrict__ b2,
                              float* __restrict__ out) {
    __shared__ union SU {
        struct { float zs[128][64]; float mus[16][64]; float rn[128]; float mun[16]; } a;
        unsigned short ehs[4][32][264];   // per-wave eh, padded row (264)
    } su;
    __shared__ float qs[128][16];
    __shared__ unsigned short w1s[256][64];   // W1t[e]: [h][d], swizzled
    __shared__ unsigned short w2s[16][256];   // W2t[e]: [c][h], swizzled
    __shared__ float b1s[256];

    const int t = threadIdx.x;
    const int lane = t & 63;
    const int w = t >> 6;
    const int g = lane >> 4;
    const int l15 = lane & 15;
    const int l7 = l15 & 7;
    const int r0 = blockIdx.x * 128;

    // P0: stage z block + mu
    {
        const float4* zsrc = (const float4*)(z + (size_t)r0 * NZ);
        float4* zdst = (float4*)&su.a.zs[0][0];
#pragma unroll
        for (int it = 0; it < 8; ++it) zdst[it * 256 + t] = zsrc[it * 256 + t];
        ((float4*)&su.a.mus[0][0])[t] = ((const float4*)mu)[t];
    }
    __syncthreads();
    // P1a: row norms |z|^2, |mu|^2
    if (t < 128) {
        float s = 0.f;
        for (int d = 0; d < NZ; ++d) { float v = su.a.zs[t][d]; s += v * v; }
        su.a.rn[t] = s;
    } else if (t < 144) {
        int k = t - 128;
        float s = 0.f;
        for (int d = 0; d < NZ; ++d) { float v = su.a.mus[k][d]; s += v * v; }
        su.a.mun[k] = s;
    }
    __syncthreads();
    // P1b: z fragments (kept for expert GEMMs) + dist via MFMA -> raw q
    bf16x8 az[2][2];
#pragma unroll
    for (int i = 0; i < 2; ++i)
#pragma unroll
        for (int ks = 0; ks < 2; ++ks) {
            int row = w * 32 + i * 16 + l15;
            int ko = ks * 32 + g * 8;
            float4 lo = *(const float4*)&su.a.zs[row][ko];
            float4 hi = *(const float4*)&su.a.zs[row][ko + 4];
            u16x8 tmp;
            tmp[0] = f2bf(lo.x); tmp[1] = f2bf(lo.y); tmp[2] = f2bf(lo.z); tmp[3] = f2bf(lo.w);
            tmp[4] = f2bf(hi.x); tmp[5] = f2bf(hi.y); tmp[6] = f2bf(hi.z); tmp[7] = f2bf(hi.w);
            az[i][ks] = __builtin_bit_cast(bf16x8, tmp);
        }
    {
        bf16x8 bmu[2];
#pragma unroll
        for (int ks = 0; ks < 2; ++ks) {
            int ko = ks * 32 + g * 8;
            float4 lo = *(const float4*)&su.a.mus[l15][ko];
            float4 hi = *(const float4*)&su.a.mus[l15][ko + 4];
            u16x8 tmp;
            tmp[0] = f2bf(lo.x); tmp[1] = f2bf(lo.y); tmp[2] = f2bf(lo.z); tmp[3] = f2bf(lo.w);
            tmp[4] = f2bf(hi.x); tmp[5] = f2bf(hi.y); tmp[6] = f2bf(hi.z); tmp[7] = f2bf(hi.w);
            bmu[ks] = __builtin_bit_cast(bf16x8, tmp);
        }
        f32x4 dacc[2] = {f32x4{0.f, 0.f, 0.f, 0.f}, f32x4{0.f, 0.f, 0.f, 0.f}};
#pragma unroll
        for (int ks = 0; ks < 2; ++ks)
#pragma unroll
            for (int i = 0; i < 2; ++i)
                dacc[i] = __builtin_amdgcn_mfma_f32_16x16x32_bf16(az[i][ks], bmu[ks], dacc[i], 0, 0, 0);
#pragma unroll
        for (int i = 0; i < 2; ++i)
#pragma unroll
            for (int r = 0; r < 4; ++r) {
                int rl = w * 32 + i * 16 + g * 4 + r;
                float dist = su.a.rn[rl] - 2.f * dacc[i][r] + su.a.mun[l15];
                qs[rl][l15] = 1.f / (1.f + dist);
            }
    }
    __syncthreads();
    // P1c: normalize q per row
    if (t < 128) {
        float s = 0.f;
#pragma unroll
        for (int k = 0; k < KE; ++k) s += qs[t][k];
        float inv = 1.f / s;
#pragma unroll
        for (int k = 0; k < KE; ++k) qs[t][k] *= inv;
    }
    __syncthreads();
    // P3: expert loop
    float pacc[2][4];
#pragma unroll
    for (int i = 0; i < 2; ++i)
#pragma unroll
        for (int r = 0; r < 4; ++r) pacc[i][r] = 0.f;

    for (int e = 0; e < KE; ++e) {
        // stage W1t[e], W2t[e], b1[e] (swizzled LDS writes)
        {
            const uint4* s1 = (const uint4*)(W1t + e * (NZ * HEXP));
#pragma unroll
            for (int it = 0; it < 8; ++it) {
                int f = it * 256 + t;
                int row = f >> 3;
                *(uint4*)&w1s[row][SWZ((f & 7) * 8, row)] = s1[f];
            }
            const uint4* s2 = (const uint4*)(W2t + e * (16 * HEXP));
#pragma unroll
            for (int it = 0; it < 2; ++it) {
                int f = it * 256 + t;
                int row = f >> 5;
                *(uint4*)&w2s[row][SWZ((f & 31) * 8, row)] = s2[f];
            }
            b1s[t] = b1[e * HEXP + t];
        }
        __syncthreads();
        // eh = relu(z @ W1[e] + b1[e]) : 32 rows x 256 per wave
        f32x4 ea[2][16];
#pragma unroll
        for (int i = 0; i < 2; ++i)
#pragma unroll
            for (int j = 0; j < 16; ++j) ea[i][j] = f32x4{0.f, 0.f, 0.f, 0.f};
#pragma unroll
        for (int ks = 0; ks < 2; ++ks) {
            const int ko = ks * 32 + g * 8;
            const int sko = SWZ(ko, l7);
#pragma unroll
            for (int j = 0; j < 16; ++j) {
                bf16x8 bw = *(const bf16x8*)&w1s[j * 16 + l15][sko];
#pragma unroll
                for (int i = 0; i < 2; ++i)
                    ea[i][j] = __builtin_amdgcn_mfma_f32_16x16x32_bf16(az[i][ks], bw, ea[i][j], 0, 0, 0);
            }
        }
        // bias + relu + bf16 -> LDS (C layout -> row-major [row][h])
#pragma unroll
        for (int j = 0; j < 16; ++j) {
            int h = j * 16 + l15;
            float bias = b1s[h];
#pragma unroll
            for (int i = 0; i < 2; ++i)
#pragma unroll
                for (int r = 0; r < 4; ++r) {
                    float v = ea[i][j][r] + bias;
                    v = v > 0.f ? v : 0.f;
                    su.ehs[w][i * 16 + g * 4 + r][h] = f2bf(v);
                }
        }
        __syncthreads();
        // logits = eh @ W2[e] (+b2) : 32 x 16 (cols 10..15 are zero-padded)
        f32x4 la[2] = {f32x4{0.f, 0.f, 0.f, 0.f}, f32x4{0.f, 0.f, 0.f, 0.f}};
#pragma unroll
        for (int ks = 0; ks < 8; ++ks) {
            const int ko = ks * 32 + g * 8;
            bf16x8 bw2 = *(const bf16x8*)&w2s[l15][SWZ(ko, l7)];
#pragma unroll
            for (int i = 0; i < 2; ++i) {
                bf16x8 ae = *(const bf16x8*)&su.ehs[w][i * 16 + l15][ko];
                la[i] = __builtin_amdgcn_mfma_f32_16x16x32_bf16(ae, bw2, la[i], 0, 0, 0);
            }
        }
        // combine: preds += q[:,e] * (logits + b2[e])
        float b2v = (l15 < NC) ? b2[e * NC + l15] : 0.f;
#pragma unroll
        for (int i = 0; i < 2; ++i)
#pragma unroll
            for (int r = 0; r < 4; ++r) {
                int rl = w * 32 + i * 16 + g * 4 + r;
                pacc[i][r] += qs[rl][e] * (la[i][r] + b2v);
            }
        __syncthreads();
    }
    // P4: store preds
    if (l15 < NC) {
#pragma unroll
        for (int i = 0; i < 2; ++i)
#pragma unroll
            for (int r = 0; r < 4; ++r) {
                int row = r0 + w * 32 + i * 16 + g * 4 + r;
                out[(size_t)row * NC + l15] = pacc[i][r];
            }
    }
}

// ---------------------------------------------------------------------------
extern "C" void kernel_launch(void* const* d_in, const int* in_sizes, int n_in,
                              void* d_out, int out_size, void* d_ws, size_t ws_size,
                              hipStream_t stream) {
    const float* X     = (const float*)d_in[0];
    const float* enc_W = (const float*)d_in[1];
    const float* enc_b = (const float*)d_in[2];
    const float* z_W   = (const float*)d_in[3];
    const float* z_b   = (const float*)d_in[4];
    const float* mu    = (const float*)d_in[5];
    const float* W1    = (const float*)d_in[6];
    const float* b1    = (const float*)d_in[7];
    const float* W2    = (const float*)d_in[8];
    const float* b2    = (const float*)d_in[9];
    float* out = (float*)d_out;

    // workspace layout (~10.2 MB)
    char* ws = (char*)d_ws;
    float*          z      = (float*)(ws);                       //  8,388,608 B
    unsigned short* enc_Wt = (unsigned short*)(ws + 8388608);    //  1,048,576 B
    unsigned short* z_Wt   = (unsigned short*)(ws + 9437184);    //     65,536 B
    unsigned short* W1t    = (unsigned short*)(ws + 9502720);    //    524,288 B
    unsigned short* W2t    = (unsigned short*)(ws + 10027008);   //    131,072 B

    prep_weights<<<dim3(3456), dim3(256), 0, stream>>>(enc_W, z_W, W1, W2,
                                                       enc_Wt, z_Wt, W1t, W2t);
    enc_fused<<<dim3(512), dim3(512), 0, stream>>>(X, enc_Wt, enc_b, z_Wt, z_b, z);
    expert_kernel<<<dim3(256), dim3(256), 0, stream>>>(z, mu, W1t, b1, W2t, b2, out);
}

// Round 2
// 173.063 us; speedup vs baseline: 1.4981x; 1.4981x over previous
//
#include <hip/hip_runtime.h>
#include <stdint.h>

// Problem constants
#define N_ROWS 32768
#define DIM    1024
#define HENC   512
#define NZ     64
#define KE     16
#define HEXP   256
#define NC     10

typedef __attribute__((ext_vector_type(8))) __bf16 bf16x8;
typedef __attribute__((ext_vector_type(4))) float f32x4;
typedef __attribute__((ext_vector_type(8))) unsigned short u16x8;
typedef __attribute__((ext_vector_type(4))) unsigned short u16x4;

__device__ __forceinline__ unsigned short f2bf(float f) {
    __bf16 h = (__bf16)f;  // RNE convert
    return __builtin_bit_cast(unsigned short, h);
}

// async global->LDS, 16B per lane. LDS dst must be wave-uniform (HW adds lane*16).
__device__ __forceinline__ void gload_lds16(void* lds, const void* gsrc) {
    __builtin_amdgcn_global_load_lds(
        (const __attribute__((address_space(1))) unsigned int*)gsrc,
        (__attribute__((address_space(3))) unsigned int*)lds,
        16, 0, 0);
}

// XOR swizzle in bf16-element space: flips 16B-granule bits 3..5 by row&7.
// Applied identically on write (or pre-swizzled global src) and read.
#define SWZ(col, row) ((col) ^ (((row) & 7) << 3))

// ---------------------------------------------------------------------------
// Kernel 0: cast+transpose all weights to bf16 so MFMA B-fragments are
// k-contiguous. enc_Wt [512][1024], z_Wt [64][512], W1t [16][256][64],
// W2t [16][16][256] (cols 10..15 zero-padded).
// ---------------------------------------------------------------------------
__global__ void prep_weights(const float* __restrict__ enc_W,
                             const float* __restrict__ z_W,
                             const float* __restrict__ W1,
                             const float* __restrict__ W2,
                             unsigned short* __restrict__ enc_Wt,
                             unsigned short* __restrict__ z_Wt,
                             unsigned short* __restrict__ W1t,
                             unsigned short* __restrict__ W2t) {
    int i = blockIdx.x * 256 + threadIdx.x;
    if (i < 524288) {                       // enc_Wt[n][k] = enc_W[k][n]
        int n = i >> 10, k = i & 1023;
        enc_Wt[i] = f2bf(enc_W[k * HENC + n]);
    } else if (i < 557056) {                // z_Wt[n][k] = z_W[k][n]
        int i2 = i - 524288;
        int n = i2 >> 9, k = i2 & 511;
        z_Wt[i2] = f2bf(z_W[k * NZ + n]);
    } else if (i < 819200) {                // W1t[e][h][d] = W1[e][d][h]
        int i3 = i - 557056;
        int e = i3 >> 14, rem = i3 & 16383;
        int h = rem >> 6, d = rem & 63;
        W1t[i3] = f2bf(W1[(e * NZ + d) * HEXP + h]);
    } else if (i < 884736) {                // W2t[e][c][h] = W2[e][h][c], pad c>=10
        int i4 = i - 819200;
        int e = i4 >> 12, rem = i4 & 4095;
        int c = rem >> 8, h = rem & 255;
        W2t[i4] = (c < NC) ? f2bf(W2[(e * HEXP + h) * NC + c]) : (unsigned short)0;
    }
}

// ---------------------------------------------------------------------------
// Kernel 1: hb = relu(X @ enc_W + enc_b) as bf16. 128x128 tile, BK=64,
// 4 waves (2x2), each wave 64x64. ROUND-2 CHANGE: double-buffered LDS +
// 2-phase pipeline (T3 minimum recipe): per step, issue next-step B
// global_load_lds and next-step X register loads BEFORE the MFMAs on the
// current buffer; cvt+ds_write the X regs after the MFMAs; single
// vmcnt(0)+barrier drain per step. X HBM latency (~900cy) and B L2 latency
// now overlap compute instead of sitting on the per-step critical path.
// XOR-swizzled LDS (T2): A via swizzled ds_write, B via global_load_lds
// with pre-swizzled source.
// ---------------------------------------------------------------------------
__launch_bounds__(256, 2)
__global__ void gemm1(const float* __restrict__ X,
                      const unsigned short* __restrict__ Bt,   // enc_Wt [512][1024]
                      const float* __restrict__ enc_b,
                      unsigned short* __restrict__ hb) {
    __shared__ unsigned short As[2][128][64];   // 32 KB
    __shared__ unsigned short Bs[2][128][64];   // 32 KB
    const int t = threadIdx.x;
    const int lane = t & 63;
    const int w = t >> 6;
    const int g = lane >> 4;
    const int l15 = lane & 15;
    const int l7 = l15 & 7;
    const int wm = (w >> 1) * 64, wn = (w & 1) * 64;

    // bijective XCD swizzle: nwg=1024, 8 XCDs, n-tile fastest within a chunk
    const int bid = blockIdx.x;
    const int wgid = (bid & 7) * 128 + (bid >> 3);
    const int m0 = (wgid >> 2) * 128;
    const int n0 = (wgid & 3) * 128;

    // A staging lanes: thread covers rows (t>>4)+16*it, cols (t&15)*4
    const int arow = t >> 4, acolq = t & 15;
    const float* aptr = X + (size_t)(m0 + arow) * DIM + acolq * 4;
    const int ascol = SWZ(acolq * 4, arow);           // swizzled dest col (elems)
    // B gload_lds lanes: 1KB chunk = 8 rows x 64 cols bf16; source pre-swizzled
    const int brow0 = lane >> 3;
    const int bsrccol = SWZ((lane & 7) * 8, brow0);
    const unsigned short* bptr = Bt + (size_t)(n0 + brow0) * DIM + bsrccol;

    f32x4 acc[4][4];
#pragma unroll
    for (int i = 0; i < 4; ++i)
#pragma unroll
        for (int j = 0; j < 4; ++j) acc[i][j] = f32x4{0.f, 0.f, 0.f, 0.f};

    // prologue: stage step 0 into buffer 0
    {
#pragma unroll
        for (int it = 0; it < 4; ++it) {
            const int chunk = it * 4 + w;
            gload_lds16(&Bs[0][chunk * 8][0], bptr + (size_t)chunk * 8 * DIM);
        }
        float4 a[8];
#pragma unroll
        for (int it = 0; it < 8; ++it)
            a[it] = *(const float4*)(aptr + (size_t)it * 16 * DIM);
#pragma unroll
        for (int it = 0; it < 8; ++it) {
            u16x4 p;
            p[0] = f2bf(a[it].x); p[1] = f2bf(a[it].y);
            p[2] = f2bf(a[it].z); p[3] = f2bf(a[it].w);
            *(u16x4*)&As[0][it * 16 + arow][ascol] = p;
        }
    }
    __syncthreads();   // drains vmcnt(0)+lgkmcnt(0): buffer 0 ready

    float4 an[8];
    for (int step = 0; step < 16; ++step) {
        const int cur = step & 1, nxt = cur ^ 1;

        // issue next-step staging FIRST (latency hides under current MFMAs)
        if (step < 15) {
            const int k1 = (step + 1) * 64;
#pragma unroll
            for (int it = 0; it < 4; ++it) {
                const int chunk = it * 4 + w;
                gload_lds16(&Bs[nxt][chunk * 8][0],
                            bptr + (size_t)chunk * 8 * DIM + k1);
            }
#pragma unroll
            for (int it = 0; it < 8; ++it)
                an[it] = *(const float4*)(aptr + (size_t)it * 16 * DIM + k1);
        }

        // compute on current buffer
#pragma unroll
        for (int kk = 0; kk < 2; ++kk) {
            const int ko = kk * 32 + g * 8;
            const int sko = SWZ(ko, l7);
            bf16x8 af[4], bfr[4];
#pragma unroll
            for (int i = 0; i < 4; ++i)
                af[i] = *(const bf16x8*)&As[cur][wm + i * 16 + l15][sko];
#pragma unroll
            for (int j = 0; j < 4; ++j)
                bfr[j] = *(const bf16x8*)&Bs[cur][wn + j * 16 + l15][sko];
#pragma unroll
            for (int i = 0; i < 4; ++i)
#pragma unroll
                for (int j = 0; j < 4; ++j)
                    acc[i][j] = __builtin_amdgcn_mfma_f32_16x16x32_bf16(af[i], bfr[j], acc[i][j], 0, 0, 0);
        }

        // convert + write next A buffer (X latency already consumed by MFMAs)
        if (step < 15) {
#pragma unroll
            for (int it = 0; it < 8; ++it) {
                u16x4 p;
                p[0] = f2bf(an[it].x); p[1] = f2bf(an[it].y);
                p[2] = f2bf(an[it].z); p[3] = f2bf(an[it].w);
                *(u16x4*)&As[nxt][it * 16 + arow][ascol] = p;
            }
        }
        __syncthreads();   // single drain per step: nxt buffers ready
    }

    // epilogue: +bias, relu, bf16 store. C layout: col=lane&15, row=(lane>>4)*4+r
#pragma unroll
    for (int j = 0; j < 4; ++j) {
        int col = n0 + wn + j * 16 + l15;
        float bias = enc_b[col];
#pragma unroll
        for (int i = 0; i < 4; ++i) {
            int rbase = m0 + wm + i * 16 + g * 4;
#pragma unroll
            for (int r = 0; r < 4; ++r) {
                float v = acc[i][j][r] + bias;
                v = v > 0.f ? v : 0.f;
                hb[(size_t)(rbase + r) * HENC + col] = f2bf(v);
            }
        }
    }
}

// ---------------------------------------------------------------------------
// Kernel 2: z = hb @ z_W + z_b (f32 out). BM=64, 512 blocks (2/CU), 4 waves
// x 16 rows. A staged via global_load_lds (pre-swizzled src), double-buffered;
// B-frags straight from L2-resident zWt, hoisted to top of step.
// ---------------------------------------------------------------------------
__launch_bounds__(256, 2)
__global__ void gemm2(const unsigned short* __restrict__ hb,
                      const unsigned short* __restrict__ zWt,   // [64][512]
                      const float* __restrict__ z_b,
                      float* __restrict__ z) {
    __shared__ unsigned short As2[2][64][64];
    const int t = threadIdx.x, lane = t & 63, w = t >> 6;
    const int g = lane >> 4, l15 = lane & 15;
    const int l7 = l15 & 7;
    const int m0 = blockIdx.x * 64;
    const int brow0 = lane >> 3;
    const int bsrccol = SWZ((lane & 7) * 8, brow0);

    f32x4 acc[4];
#pragma unroll
    for (int j = 0; j < 4; ++j) acc[j] = f32x4{0.f, 0.f, 0.f, 0.f};

    // prologue: stage step 0 (64x64 bf16 = 8 chunks; 2 per wave)
#pragma unroll
    for (int it = 0; it < 2; ++it) {
        const int chunk = it * 4 + w;
        gload_lds16(&As2[0][chunk * 8][0],
                    hb + (size_t)(m0 + chunk * 8 + brow0) * HENC + bsrccol);
    }
    __syncthreads();

    for (int step = 0; step < 8; ++step) {
        const int cur = step & 1, nxt = cur ^ 1;
        // B frags for this step first (full step to cover L2 latency)
        bf16x8 bfr[2][4];
#pragma unroll
        for (int kk = 0; kk < 2; ++kk) {
            const int kg = step * 64 + kk * 32 + g * 8;
#pragma unroll
            for (int j = 0; j < 4; ++j)
                bfr[kk][j] = *(const bf16x8*)(zWt + (size_t)(j * 16 + l15) * HENC + kg);
        }
        if (step < 7) {
            const int k1 = (step + 1) * 64;
#pragma unroll
            for (int it = 0; it < 2; ++it) {
                const int chunk = it * 4 + w;
                gload_lds16(&As2[nxt][chunk * 8][0],
                            hb + (size_t)(m0 + chunk * 8 + brow0) * HENC + k1 + bsrccol);
            }
        }
#pragma unroll
        for (int kk = 0; kk < 2; ++kk) {
            const int ko = kk * 32 + g * 8;
            bf16x8 af = *(const bf16x8*)&As2[cur][w * 16 + l15][SWZ(ko, l7)];
#pragma unroll
            for (int j = 0; j < 4; ++j)
                acc[j] = __builtin_amdgcn_mfma_f32_16x16x32_bf16(af, bfr[kk][j], acc[j], 0, 0, 0);
        }
        __syncthreads();
    }
#pragma unroll
    for (int j = 0; j < 4; ++j) {
        int col = j * 16 + l15;
        float bias = z_b[col];
#pragma unroll
        for (int r = 0; r < 4; ++r) {
            int row = m0 + w * 16 + g * 4 + r;
            z[(size_t)row * NZ + col] = acc[j][r] + bias;
        }
    }
}

// ---------------------------------------------------------------------------
// Kernel 3: fused q + experts + combine. 256 blocks (1/CU), 128 rows each.
// dist via MFMA (|z|^2 - 2 z@mu^T + |mu|^2), per-expert 64->256->10 MLP via
// MFMA with eh LDS round-trip, preds accumulated in registers.
// w1s/w2s XOR-swizzled (write and read) to kill fragment-read conflicts.
// ---------------------------------------------------------------------------
__launch_bounds__(256, 1)
__global__ void expert_kernel(const float* __restrict__ z,
                              const float* __restrict__ mu,
                              const unsigned short* __restrict__ W1t,  // [16][256][64]
                              const float* __restrict__ b1,
                              const unsigned short* __restrict__ W2t,  // [16][16][256]
                              const float* __restrict__ b2,
                              float* __restrict__ out) {
    __shared__ union SU {
        struct { float zs[128][64]; float mus[16][64]; float rn[128]; float mun[16]; } a;
        unsigned short ehs[4][32][264];   // per-wave eh, padded row (264)
    } su;
    __shared__ float qs[128][16];
    __shared__ unsigned short w1s[256][64];   // W1t[e]: [h][d], swizzled
    __shared__ unsigned short w2s[16][256];   // W2t[e]: [c][h], swizzled
    __shared__ float b1s[256];

    const int t = threadIdx.x;
    const int lane = t & 63;
    const int w = t >> 6;
    const int g = lane >> 4;
    const int l15 = lane & 15;
    const int l7 = l15 & 7;
    const int r0 = blockIdx.x * 128;

    // P0: stage z block + mu
    {
        const float4* zsrc = (const float4*)(z + (size_t)r0 * NZ);
        float4* zdst = (float4*)&su.a.zs[0][0];
#pragma unroll
        for (int it = 0; it < 8; ++it) zdst[it * 256 + t] = zsrc[it * 256 + t];
        ((float4*)&su.a.mus[0][0])[t] = ((const float4*)mu)[t];
    }
    __syncthreads();
    // P1a: row norms |z|^2, |mu|^2
    if (t < 128) {
        float s = 0.f;
        for (int d = 0; d < NZ; ++d) { float v = su.a.zs[t][d]; s += v * v; }
        su.a.rn[t] = s;
    } else if (t < 144) {
        int k = t - 128;
        float s = 0.f;
        for (int d = 0; d < NZ; ++d) { float v = su.a.mus[k][d]; s += v * v; }
        su.a.mun[k] = s;
    }
    __syncthreads();
    // P1b: z fragments (kept for expert GEMMs) + dist via MFMA -> raw q
    bf16x8 az[2][2];
#pragma unroll
    for (int i = 0; i < 2; ++i)
#pragma unroll
        for (int ks = 0; ks < 2; ++ks) {
            int row = w * 32 + i * 16 + l15;
            int ko = ks * 32 + g * 8;
            float4 lo = *(const float4*)&su.a.zs[row][ko];
            float4 hi = *(const float4*)&su.a.zs[row][ko + 4];
            u16x8 tmp;
            tmp[0] = f2bf(lo.x); tmp[1] = f2bf(lo.y); tmp[2] = f2bf(lo.z); tmp[3] = f2bf(lo.w);
            tmp[4] = f2bf(hi.x); tmp[5] = f2bf(hi.y); tmp[6] = f2bf(hi.z); tmp[7] = f2bf(hi.w);
            az[i][ks] = __builtin_bit_cast(bf16x8, tmp);
        }
    {
        bf16x8 bmu[2];
#pragma unroll
        for (int ks = 0; ks < 2; ++ks) {
            int ko = ks * 32 + g * 8;
            float4 lo = *(const float4*)&su.a.mus[l15][ko];
            float4 hi = *(const float4*)&su.a.mus[l15][ko + 4];
            u16x8 tmp;
            tmp[0] = f2bf(lo.x); tmp[1] = f2bf(lo.y); tmp[2] = f2bf(lo.z); tmp[3] = f2bf(lo.w);
            tmp[4] = f2bf(hi.x); tmp[5] = f2bf(hi.y); tmp[6] = f2bf(hi.z); tmp[7] = f2bf(hi.w);
            bmu[ks] = __builtin_bit_cast(bf16x8, tmp);
        }
        f32x4 dacc[2] = {f32x4{0.f, 0.f, 0.f, 0.f}, f32x4{0.f, 0.f, 0.f, 0.f}};
#pragma unroll
        for (int ks = 0; ks < 2; ++ks)
#pragma unroll
            for (int i = 0; i < 2; ++i)
                dacc[i] = __builtin_amdgcn_mfma_f32_16x16x32_bf16(az[i][ks], bmu[ks], dacc[i], 0, 0, 0);
#pragma unroll
        for (int i = 0; i < 2; ++i)
#pragma unroll
            for (int r = 0; r < 4; ++r) {
                int rl = w * 32 + i * 16 + g * 4 + r;
                float dist = su.a.rn[rl] - 2.f * dacc[i][r] + su.a.mun[l15];
                qs[rl][l15] = 1.f / (1.f + dist);
            }
    }
    __syncthreads();
    // P1c: normalize q per row
    if (t < 128) {
        float s = 0.f;
#pragma unroll
        for (int k = 0; k < KE; ++k) s += qs[t][k];
        float inv = 1.f / s;
#pragma unroll
        for (int k = 0; k < KE; ++k) qs[t][k] *= inv;
    }
    __syncthreads();
    // P3: expert loop
    float pacc[2][4];
#pragma unroll
    for (int i = 0; i < 2; ++i)
#pragma unroll
        for (int r = 0; r < 4; ++r) pacc[i][r] = 0.f;

    for (int e = 0; e < KE; ++e) {
        // stage W1t[e], W2t[e], b1[e] (swizzled LDS writes)
        {
            const uint4* s1 = (const uint4*)(W1t + e * (NZ * HEXP));
#pragma unroll
            for (int it = 0; it < 8; ++it) {
                int f = it * 256 + t;
                int row = f >> 3;
                *(uint4*)&w1s[row][SWZ((f & 7) * 8, row)] = s1[f];
            }
            const uint4* s2 = (const uint4*)(W2t + e * (16 * HEXP));
#pragma unroll
            for (int it = 0; it < 2; ++it) {
                int f = it * 256 + t;
                int row = f >> 5;
                *(uint4*)&w2s[row][SWZ((f & 31) * 8, row)] = s2[f];
            }
            b1s[t] = b1[e * HEXP + t];
        }
        __syncthreads();
        // eh = relu(z @ W1[e] + b1[e]) : 32 rows x 256 per wave
        f32x4 ea[2][16];
#pragma unroll
        for (int i = 0; i < 2; ++i)
#pragma unroll
            for (int j = 0; j < 16; ++j) ea[i][j] = f32x4{0.f, 0.f, 0.f, 0.f};
#pragma unroll
        for (int ks = 0; ks < 2; ++ks) {
            const int ko = ks * 32 + g * 8;
            const int sko = SWZ(ko, l7);
#pragma unroll
            for (int j = 0; j < 16; ++j) {
                bf16x8 bw = *(const bf16x8*)&w1s[j * 16 + l15][sko];
#pragma unroll
                for (int i = 0; i < 2; ++i)
                    ea[i][j] = __builtin_amdgcn_mfma_f32_16x16x32_bf16(az[i][ks], bw, ea[i][j], 0, 0, 0);
            }
        }
        // bias + relu + bf16 -> LDS (C layout -> row-major [row][h])
#pragma unroll
        for (int j = 0; j < 16; ++j) {
            int h = j * 16 + l15;
            float bias = b1s[h];
#pragma unroll
            for (int i = 0; i < 2; ++i)
#pragma unroll
                for (int r = 0; r < 4; ++r) {
                    float v = ea[i][j][r] + bias;
                    v = v > 0.f ? v : 0.f;
                    su.ehs[w][i * 16 + g * 4 + r][h] = f2bf(v);
                }
        }
        __syncthreads();
        // logits = eh @ W2[e] (+b2) : 32 x 16 (cols 10..15 are zero-padded)
        f32x4 la[2] = {f32x4{0.f, 0.f, 0.f, 0.f}, f32x4{0.f, 0.f, 0.f, 0.f}};
#pragma unroll
        for (int ks = 0; ks < 8; ++ks) {
            const int ko = ks * 32 + g * 8;
            bf16x8 bw2 = *(const bf16x8*)&w2s[l15][SWZ(ko, l7)];
#pragma unroll
            for (int i = 0; i < 2; ++i) {
                bf16x8 ae = *(const bf16x8*)&su.ehs[w][i * 16 + l15][ko];
                la[i] = __builtin_amdgcn_mfma_f32_16x16x32_bf16(ae, bw2, la[i], 0, 0, 0);
            }
        }
        // combine: preds += q[:,e] * (logits + b2[e])
        float b2v = (l15 < NC) ? b2[e * NC + l15] : 0.f;
#pragma unroll
        for (int i = 0; i < 2; ++i)
#pragma unroll
            for (int r = 0; r < 4; ++r) {
                int rl = w * 32 + i * 16 + g * 4 + r;
                pacc[i][r] += qs[rl][e] * (la[i][r] + b2v);
            }
        __syncthreads();
    }
    // P4: store preds
    if (l15 < NC) {
#pragma unroll
        for (int i = 0; i < 2; ++i)
#pragma unroll
            for (int r = 0; r < 4; ++r) {
                int row = r0 + w * 32 + i * 16 + g * 4 + r;
                out[(size_t)row * NC + l15] = pacc[i][r];
            }
    }
}

// ---------------------------------------------------------------------------
extern "C" void kernel_launch(void* const* d_in, const int* in_sizes, int n_in,
                              void* d_out, int out_size, void* d_ws, size_t ws_size,
                              hipStream_t stream) {
    const float* X     = (const float*)d_in[0];
    const float* enc_W = (const float*)d_in[1];
    const float* enc_b = (const float*)d_in[2];
    const float* z_W   = (const float*)d_in[3];
    const float* z_b   = (const float*)d_in[4];
    const float* mu    = (const float*)d_in[5];
    const float* W1    = (const float*)d_in[6];
    const float* b1    = (const float*)d_in[7];
    const float* W2    = (const float*)d_in[8];
    const float* b2    = (const float*)d_in[9];
    float* out = (float*)d_out;

    // workspace layout (total ~43.7 MB)
    char* ws = (char*)d_ws;
    unsigned short* hb     = (unsigned short*)(ws);              // 33,554,432 B
    float*          z      = (float*)(ws + 33554432);            //  8,388,608 B
    unsigned short* enc_Wt = (unsigned short*)(ws + 41943040);   //  1,048,576 B
    unsigned short* z_Wt   = (unsigned short*)(ws + 42991616);   //     65,536 B
    unsigned short* W1t    = (unsigned short*)(ws + 43057152);   //    524,288 B
    unsigned short* W2t    = (unsigned short*)(ws + 43581440);   //    131,072 B

    prep_weights<<<dim3(3456), dim3(256), 0, stream>>>(enc_W, z_W, W1, W2,
                                                       enc_Wt, z_Wt, W1t, W2t);
    gemm1<<<dim3(1024), dim3(256), 0, stream>>>(X, enc_Wt, enc_b, hb);
    gemm2<<<dim3(512), dim3(256), 0, stream>>>(hb, z_Wt, z_b, z);
    expert_kernel<<<dim3(256), dim3(256), 0, stream>>>(z, mu, W1t, b1, W2t, b2, out);
}

// Round 3
// 149.774 us; speedup vs baseline: 1.7310x; 1.1555x over previous
//
#include <hip/hip_runtime.h>
#include <stdint.h>

// Problem constants
#define N_ROWS 32768
#define DIM    1024
#define HENC   512
#define NZ     64
#define KE     16
#define HEXP   256
#define NC     10

typedef __attribute__((ext_vector_type(8))) __bf16 bf16x8;
typedef __attribute__((ext_vector_type(4))) float f32x4;
typedef __attribute__((ext_vector_type(8))) unsigned short u16x8;
typedef __attribute__((ext_vector_type(4))) unsigned short u16x4;

__device__ __forceinline__ unsigned short f2bf(float f) {
    __bf16 h = (__bf16)f;  // RNE convert
    return __builtin_bit_cast(unsigned short, h);
}

// async global->LDS, 16B per lane. LDS dst must be wave-uniform (HW adds lane*16).
__device__ __forceinline__ void gload_lds16(void* lds, const void* gsrc) {
    __builtin_amdgcn_global_load_lds(
        (const __attribute__((address_space(1))) unsigned int*)gsrc,
        (__attribute__((address_space(3))) unsigned int*)lds,
        16, 0, 0);
}

// XOR swizzle in bf16-element space: flips 16B-granule bits 3..5 by row&7.
// Applied identically on write (or pre-swizzled global src) and read.
#define SWZ(col, row) ((col) ^ (((row) & 7) << 3))

// ---------------------------------------------------------------------------
// Kernel 0: cast+transpose all weights to bf16 so MFMA B-fragments are
// k-contiguous. enc_Wt [512][1024], z_Wt [64][512], W1t [16][256][64],
// W2t [16][16][256] (cols 10..15 zero-padded).
// ---------------------------------------------------------------------------
__global__ void prep_weights(const float* __restrict__ enc_W,
                             const float* __restrict__ z_W,
                             const float* __restrict__ W1,
                             const float* __restrict__ W2,
                             unsigned short* __restrict__ enc_Wt,
                             unsigned short* __restrict__ z_Wt,
                             unsigned short* __restrict__ W1t,
                             unsigned short* __restrict__ W2t) {
    int i = blockIdx.x * 256 + threadIdx.x;
    if (i < 524288) {                       // enc_Wt[n][k] = enc_W[k][n]
        int n = i >> 10, k = i & 1023;
        enc_Wt[i] = f2bf(enc_W[k * HENC + n]);
    } else if (i < 557056) {                // z_Wt[n][k] = z_W[k][n]
        int i2 = i - 524288;
        int n = i2 >> 9, k = i2 & 511;
        z_Wt[i2] = f2bf(z_W[k * NZ + n]);
    } else if (i < 819200) {                // W1t[e][h][d] = W1[e][d][h]
        int i3 = i - 557056;
        int e = i3 >> 14, rem = i3 & 16383;
        int h = rem >> 6, d = rem & 63;
        W1t[i3] = f2bf(W1[(e * NZ + d) * HEXP + h]);
    } else if (i < 884736) {                // W2t[e][c][h] = W2[e][h][c], pad c>=10
        int i4 = i - 819200;
        int e = i4 >> 12, rem = i4 & 4095;
        int c = rem >> 8, h = rem & 255;
        W2t[i4] = (c < NC) ? f2bf(W2[(e * HEXP + h) * NC + c]) : (unsigned short)0;
    }
}

// ---------------------------------------------------------------------------
// Kernel 1: hb = relu(X @ enc_W + enc_b) as bf16.
// ROUND-3 SHAPE: BM=128 x BN=256, BK=64. 4 waves (2x2), wave tile 64x128,
// acc[4][8] (64 MFMA/wave/step -- 2x the compute per step to hide latency
// under). Grid 512 = exactly 2 blocks/CU resident (80 KB LDS). X redundancy
// through L3 halves (4x -> 2x). A (X f32) single-buffered 16 KB with
// register prefetch: next-step f32 loads issued BEFORE the MFMAs, converted
// and written after barrier1 (T14 issue-early/write-late). B double-buffered
// 64 KB via global_load_lds issued before the MFMAs (L2 latency hidden).
// XOR-swizzled LDS both sides.
// ---------------------------------------------------------------------------
__launch_bounds__(256, 2)
__global__ void gemm1(const float* __restrict__ X,
                      const unsigned short* __restrict__ Bt,   // enc_Wt [512][1024]
                      const float* __restrict__ enc_b,
                      unsigned short* __restrict__ hb) {
    __shared__ unsigned short As[128][64];        // 16 KB, single-buffered
    __shared__ unsigned short Bs[2][256][64];     // 64 KB, double-buffered
    const int t = threadIdx.x;
    const int lane = t & 63;
    const int w = t >> 6;
    const int g = lane >> 4;
    const int l15 = lane & 15;
    const int l7 = l15 & 7;
    const int wm = (w >> 1) * 64;        // wave row base (0/64)
    const int wn = (w & 1) * 128;        // wave col base (0/128)

    // bijective XCD swizzle: nwg=512, 8 XCDs
    const int bid = blockIdx.x;
    const int wgid = (bid & 7) * 64 + (bid >> 3);
    const int m0 = (wgid >> 1) * 128;
    const int n0 = (wgid & 1) * 256;

    // A staging lanes: thread covers rows (t>>4)+16*it, cols (t&15)*4
    const int arow = t >> 4, acolq = t & 15;
    const float* aptr = X + (size_t)(m0 + arow) * DIM + acolq * 4;
    const int ascol = SWZ(acolq * 4, arow);           // swizzled dest col (elems)
    // B gload_lds lanes: 1KB chunk = 8 rows x 64 cols bf16; source pre-swizzled
    const int brow0 = lane >> 3;
    const int bsrccol = SWZ((lane & 7) * 8, brow0);
    const unsigned short* bptr = Bt + (size_t)(n0 + brow0) * DIM + bsrccol;

    f32x4 acc[4][8];
#pragma unroll
    for (int i = 0; i < 4; ++i)
#pragma unroll
        for (int j = 0; j < 8; ++j) acc[i][j] = f32x4{0.f, 0.f, 0.f, 0.f};

    // prologue: stage step 0 (B into buf 0, A into As)
    {
#pragma unroll
        for (int it = 0; it < 8; ++it) {
            const int chunk = it * 4 + w;           // 32 chunks of 8 rows
            gload_lds16(&Bs[0][chunk * 8][0], bptr + (size_t)chunk * 8 * DIM);
        }
        float4 a[8];
#pragma unroll
        for (int it = 0; it < 8; ++it)
            a[it] = *(const float4*)(aptr + (size_t)it * 16 * DIM);
#pragma unroll
        for (int it = 0; it < 8; ++it) {
            u16x4 p;
            p[0] = f2bf(a[it].x); p[1] = f2bf(a[it].y);
            p[2] = f2bf(a[it].z); p[3] = f2bf(a[it].w);
            *(u16x4*)&As[it * 16 + arow][ascol] = p;
        }
    }
    __syncthreads();

    float4 an[8];
    for (int step = 0; step < 16; ++step) {
        const int cur = step & 1, nxt = cur ^ 1;

        // issue next-step staging FIRST: B -> Bs[nxt] (async LDS), A -> regs
        if (step < 15) {
            const int k1 = (step + 1) * 64;
#pragma unroll
            for (int it = 0; it < 8; ++it) {
                const int chunk = it * 4 + w;
                gload_lds16(&Bs[nxt][chunk * 8][0],
                            bptr + (size_t)chunk * 8 * DIM + k1);
            }
#pragma unroll
            for (int it = 0; it < 8; ++it)
                an[it] = *(const float4*)(aptr + (size_t)it * 16 * DIM + k1);
        }

        // compute on current buffers: 2 kk halves x (4 row x 8 col) MFMA
#pragma unroll
        for (int kk = 0; kk < 2; ++kk) {
            const int ko = kk * 32 + g * 8;
            const int sko = SWZ(ko, l7);
            bf16x8 af[4], bfr[8];
#pragma unroll
            for (int i = 0; i < 4; ++i)
                af[i] = *(const bf16x8*)&As[wm + i * 16 + l15][sko];
#pragma unroll
            for (int j = 0; j < 8; ++j)
                bfr[j] = *(const bf16x8*)&Bs[cur][wn + j * 16 + l15][sko];
#pragma unroll
            for (int i = 0; i < 4; ++i)
#pragma unroll
                for (int j = 0; j < 8; ++j)
                    acc[i][j] = __builtin_amdgcn_mfma_f32_16x16x32_bf16(af[i], bfr[j], acc[i][j], 0, 0, 0);
        }
        __syncthreads();   // barrier1: all waves done reading As (and Bs[nxt] landed)

        // overwrite As with next step's A (X latency consumed by the MFMAs)
        if (step < 15) {
#pragma unroll
            for (int it = 0; it < 8; ++it) {
                u16x4 p;
                p[0] = f2bf(an[it].x); p[1] = f2bf(an[it].y);
                p[2] = f2bf(an[it].z); p[3] = f2bf(an[it].w);
                *(u16x4*)&As[it * 16 + arow][ascol] = p;
            }
        }
        __syncthreads();   // barrier2: As ready for next step
    }

    // epilogue: +bias, relu, bf16 store. C layout: col=lane&15, row=(lane>>4)*4+r
#pragma unroll
    for (int j = 0; j < 8; ++j) {
        int col = n0 + wn + j * 16 + l15;
        float bias = enc_b[col];
#pragma unroll
        for (int i = 0; i < 4; ++i) {
            int rbase = m0 + wm + i * 16 + g * 4;
#pragma unroll
            for (int r = 0; r < 4; ++r) {
                float v = acc[i][j][r] + bias;
                v = v > 0.f ? v : 0.f;
                hb[(size_t)(rbase + r) * HENC + col] = f2bf(v);
            }
        }
    }
}

// ---------------------------------------------------------------------------
// Kernel 2: z = hb @ z_W + z_b (f32 out). BM=64, 512 blocks (2/CU), 4 waves
// x 16 rows. A staged via global_load_lds (pre-swizzled src), double-buffered;
// B-frags straight from L2-resident zWt, hoisted to top of step.
// ---------------------------------------------------------------------------
__launch_bounds__(256, 2)
__global__ void gemm2(const unsigned short* __restrict__ hb,
                      const unsigned short* __restrict__ zWt,   // [64][512]
                      const float* __restrict__ z_b,
                      float* __restrict__ z) {
    __shared__ unsigned short As2[2][64][64];
    const int t = threadIdx.x, lane = t & 63, w = t >> 6;
    const int g = lane >> 4, l15 = lane & 15;
    const int l7 = l15 & 7;
    const int m0 = blockIdx.x * 64;
    const int brow0 = lane >> 3;
    const int bsrccol = SWZ((lane & 7) * 8, brow0);

    f32x4 acc[4];
#pragma unroll
    for (int j = 0; j < 4; ++j) acc[j] = f32x4{0.f, 0.f, 0.f, 0.f};

    // prologue: stage step 0 (64x64 bf16 = 8 chunks; 2 per wave)
#pragma unroll
    for (int it = 0; it < 2; ++it) {
        const int chunk = it * 4 + w;
        gload_lds16(&As2[0][chunk * 8][0],
                    hb + (size_t)(m0 + chunk * 8 + brow0) * HENC + bsrccol);
    }
    __syncthreads();

    for (int step = 0; step < 8; ++step) {
        const int cur = step & 1, nxt = cur ^ 1;
        // B frags for this step first (full step to cover L2 latency)
        bf16x8 bfr[2][4];
#pragma unroll
        for (int kk = 0; kk < 2; ++kk) {
            const int kg = step * 64 + kk * 32 + g * 8;
#pragma unroll
            for (int j = 0; j < 4; ++j)
                bfr[kk][j] = *(const bf16x8*)(zWt + (size_t)(j * 16 + l15) * HENC + kg);
        }
        if (step < 7) {
            const int k1 = (step + 1) * 64;
#pragma unroll
            for (int it = 0; it < 2; ++it) {
                const int chunk = it * 4 + w;
                gload_lds16(&As2[nxt][chunk * 8][0],
                            hb + (size_t)(m0 + chunk * 8 + brow0) * HENC + k1 + bsrccol);
            }
        }
#pragma unroll
        for (int kk = 0; kk < 2; ++kk) {
            const int ko = kk * 32 + g * 8;
            bf16x8 af = *(const bf16x8*)&As2[cur][w * 16 + l15][SWZ(ko, l7)];
#pragma unroll
            for (int j = 0; j < 4; ++j)
                acc[j] = __builtin_amdgcn_mfma_f32_16x16x32_bf16(af, bfr[kk][j], acc[j], 0, 0, 0);
        }
        __syncthreads();
    }
#pragma unroll
    for (int j = 0; j < 4; ++j) {
        int col = j * 16 + l15;
        float bias = z_b[col];
#pragma unroll
        for (int r = 0; r < 4; ++r) {
            int row = m0 + w * 16 + g * 4 + r;
            z[(size_t)row * NZ + col] = acc[j][r] + bias;
        }
    }
}

// ---------------------------------------------------------------------------
// Kernel 3: fused q + experts + combine. 256 blocks (1/CU), 128 rows each.
// dist via MFMA (|z|^2 - 2 z@mu^T + |mu|^2), per-expert 64->256->10 MLP via
// MFMA with eh LDS round-trip, preds accumulated in registers.
// w1s/w2s XOR-swizzled (write and read) to kill fragment-read conflicts.
// ---------------------------------------------------------------------------
__launch_bounds__(256, 1)
__global__ void expert_kernel(const float* __restrict__ z,
                              const float* __restrict__ mu,
                              const unsigned short* __restrict__ W1t,  // [16][256][64]
                              const float* __restrict__ b1,
                              const unsigned short* __restrict__ W2t,  // [16][16][256]
                              const float* __restrict__ b2,
                              float* __restrict__ out) {
    __shared__ union SU {
        struct { float zs[128][64]; float mus[16][64]; float rn[128]; float mun[16]; } a;
        unsigned short ehs[4][32][264];   // per-wave eh, padded row (264)
    } su;
    __shared__ float qs[128][16];
    __shared__ unsigned short w1s[256][64];   // W1t[e]: [h][d], swizzled
    __shared__ unsigned short w2s[16][256];   // W2t[e]: [c][h], swizzled
    __shared__ float b1s[256];

    const int t = threadIdx.x;
    const int lane = t & 63;
    const int w = t >> 6;
    const int g = lane >> 4;
    const int l15 = lane & 15;
    const int l7 = l15 & 7;
    const int r0 = blockIdx.x * 128;

    // P0: stage z block + mu
    {
        const float4* zsrc = (const float4*)(z + (size_t)r0 * NZ);
        float4* zdst = (float4*)&su.a.zs[0][0];
#pragma unroll
        for (int it = 0; it < 8; ++it) zdst[it * 256 + t] = zsrc[it * 256 + t];
        ((float4*)&su.a.mus[0][0])[t] = ((const float4*)mu)[t];
    }
    __syncthreads();
    // P1a: row norms |z|^2, |mu|^2
    if (t < 128) {
        float s = 0.f;
        for (int d = 0; d < NZ; ++d) { float v = su.a.zs[t][d]; s += v * v; }
        su.a.rn[t] = s;
    } else if (t < 144) {
        int k = t - 128;
        float s = 0.f;
        for (int d = 0; d < NZ; ++d) { float v = su.a.mus[k][d]; s += v * v; }
        su.a.mun[k] = s;
    }
    __syncthreads();
    // P1b: z fragments (kept for expert GEMMs) + dist via MFMA -> raw q
    bf16x8 az[2][2];
#pragma unroll
    for (int i = 0; i < 2; ++i)
#pragma unroll
        for (int ks = 0; ks < 2; ++ks) {
            int row = w * 32 + i * 16 + l15;
            int ko = ks * 32 + g * 8;
            float4 lo = *(const float4*)&su.a.zs[row][ko];
            float4 hi = *(const float4*)&su.a.zs[row][ko + 4];
            u16x8 tmp;
            tmp[0] = f2bf(lo.x); tmp[1] = f2bf(lo.y); tmp[2] = f2bf(lo.z); tmp[3] = f2bf(lo.w);
            tmp[4] = f2bf(hi.x); tmp[5] = f2bf(hi.y); tmp[6] = f2bf(hi.z); tmp[7] = f2bf(hi.w);
            az[i][ks] = __builtin_bit_cast(bf16x8, tmp);
        }
    {
        bf16x8 bmu[2];
#pragma unroll
        for (int ks = 0; ks < 2; ++ks) {
            int ko = ks * 32 + g * 8;
            float4 lo = *(const float4*)&su.a.mus[l15][ko];
            float4 hi = *(const float4*)&su.a.mus[l15][ko + 4];
            u16x8 tmp;
            tmp[0] = f2bf(lo.x); tmp[1] = f2bf(lo.y); tmp[2] = f2bf(lo.z); tmp[3] = f2bf(lo.w);
            tmp[4] = f2bf(hi.x); tmp[5] = f2bf(hi.y); tmp[6] = f2bf(hi.z); tmp[7] = f2bf(hi.w);
            bmu[ks] = __builtin_bit_cast(bf16x8, tmp);
        }
        f32x4 dacc[2] = {f32x4{0.f, 0.f, 0.f, 0.f}, f32x4{0.f, 0.f, 0.f, 0.f}};
#pragma unroll
        for (int ks = 0; ks < 2; ++ks)
#pragma unroll
            for (int i = 0; i < 2; ++i)
                dacc[i] = __builtin_amdgcn_mfma_f32_16x16x32_bf16(az[i][ks], bmu[ks], dacc[i], 0, 0, 0);
#pragma unroll
        for (int i = 0; i < 2; ++i)
#pragma unroll
            for (int r = 0; r < 4; ++r) {
                int rl = w * 32 + i * 16 + g * 4 + r;
                float dist = su.a.rn[rl] - 2.f * dacc[i][r] + su.a.mun[l15];
                qs[rl][l15] = 1.f / (1.f + dist);
            }
    }
    __syncthreads();
    // P1c: normalize q per row
    if (t < 128) {
        float s = 0.f;
#pragma unroll
        for (int k = 0; k < KE; ++k) s += qs[t][k];
        float inv = 1.f / s;
#pragma unroll
        for (int k = 0; k < KE; ++k) qs[t][k] *= inv;
    }
    __syncthreads();
    // P3: expert loop
    float pacc[2][4];
#pragma unroll
    for (int i = 0; i < 2; ++i)
#pragma unroll
        for (int r = 0; r < 4; ++r) pacc[i][r] = 0.f;

    for (int e = 0; e < KE; ++e) {
        // stage W1t[e], W2t[e], b1[e] (swizzled LDS writes)
        {
            const uint4* s1 = (const uint4*)(W1t + e * (NZ * HEXP));
#pragma unroll
            for (int it = 0; it < 8; ++it) {
                int f = it * 256 + t;
                int row = f >> 3;
                *(uint4*)&w1s[row][SWZ((f & 7) * 8, row)] = s1[f];
            }
            const uint4* s2 = (const uint4*)(W2t + e * (16 * HEXP));
#pragma unroll
            for (int it = 0; it < 2; ++it) {
                int f = it * 256 + t;
                int row = f >> 5;
                *(uint4*)&w2s[row][SWZ((f & 31) * 8, row)] = s2[f];
            }
            b1s[t] = b1[e * HEXP + t];
        }
        __syncthreads();
        // eh = relu(z @ W1[e] + b1[e]) : 32 rows x 256 per wave
        f32x4 ea[2][16];
#pragma unroll
        for (int i = 0; i < 2; ++i)
#pragma unroll
            for (int j = 0; j < 16; ++j) ea[i][j] = f32x4{0.f, 0.f, 0.f, 0.f};
#pragma unroll
        for (int ks = 0; ks < 2; ++ks) {
            const int ko = ks * 32 + g * 8;
            const int sko = SWZ(ko, l7);
#pragma unroll
            for (int j = 0; j < 16; ++j) {
                bf16x8 bw = *(const bf16x8*)&w1s[j * 16 + l15][sko];
#pragma unroll
                for (int i = 0; i < 2; ++i)
                    ea[i][j] = __builtin_amdgcn_mfma_f32_16x16x32_bf16(az[i][ks], bw, ea[i][j], 0, 0, 0);
            }
        }
        // bias + relu + bf16 -> LDS (C layout -> row-major [row][h])
#pragma unroll
        for (int j = 0; j < 16; ++j) {
            int h = j * 16 + l15;
            float bias = b1s[h];
#pragma unroll
            for (int i = 0; i < 2; ++i)
#pragma unroll
                for (int r = 0; r < 4; ++r) {
                    float v = ea[i][j][r] + bias;
                    v = v > 0.f ? v : 0.f;
                    su.ehs[w][i * 16 + g * 4 + r][h] = f2bf(v);
                }
        }
        __syncthreads();
        // logits = eh @ W2[e] (+b2) : 32 x 16 (cols 10..15 are zero-padded)
        f32x4 la[2] = {f32x4{0.f, 0.f, 0.f, 0.f}, f32x4{0.f, 0.f, 0.f, 0.f}};
#pragma unroll
        for (int ks = 0; ks < 8; ++ks) {
            const int ko = ks * 32 + g * 8;
            bf16x8 bw2 = *(const bf16x8*)&w2s[l15][SWZ(ko, l7)];
#pragma unroll
            for (int i = 0; i < 2; ++i) {
                bf16x8 ae = *(const bf16x8*)&su.ehs[w][i * 16 + l15][ko];
                la[i] = __builtin_amdgcn_mfma_f32_16x16x32_bf16(ae, bw2, la[i], 0, 0, 0);
            }
        }
        // combine: preds += q[:,e] * (logits + b2[e])
        float b2v = (l15 < NC) ? b2[e * NC + l15] : 0.f;
#pragma unroll
        for (int i = 0; i < 2; ++i)
#pragma unroll
            for (int r = 0; r < 4; ++r) {
                int rl = w * 32 + i * 16 + g * 4 + r;
                pacc[i][r] += qs[rl][e] * (la[i][r] + b2v);
            }
        __syncthreads();
    }
    // P4: store preds
    if (l15 < NC) {
#pragma unroll
        for (int i = 0; i < 2; ++i)
#pragma unroll
            for (int r = 0; r < 4; ++r) {
                int row = r0 + w * 32 + i * 16 + g * 4 + r;
                out[(size_t)row * NC + l15] = pacc[i][r];
            }
    }
}

// ---------------------------------------------------------------------------
extern "C" void kernel_launch(void* const* d_in, const int* in_sizes, int n_in,
                              void* d_out, int out_size, void* d_ws, size_t ws_size,
                              hipStream_t stream) {
    const float* X     = (const float*)d_in[0];
    const float* enc_W = (const float*)d_in[1];
    const float* enc_b = (const float*)d_in[2];
    const float* z_W   = (const float*)d_in[3];
    const float* z_b   = (const float*)d_in[4];
    const float* mu    = (const float*)d_in[5];
    const float* W1    = (const float*)d_in[6];
    const float* b1    = (const float*)d_in[7];
    const float* W2    = (const float*)d_in[8];
    const float* b2    = (const float*)d_in[9];
    float* out = (float*)d_out;

    // workspace layout (total ~43.7 MB)
    char* ws = (char*)d_ws;
    unsigned short* hb     = (unsigned short*)(ws);              // 33,554,432 B
    float*          z      = (float*)(ws + 33554432);            //  8,388,608 B
    unsigned short* enc_Wt = (unsigned short*)(ws + 41943040);   //  1,048,576 B
    unsigned short* z_Wt   = (unsigned short*)(ws + 42991616);   //     65,536 B
    unsigned short* W1t    = (unsigned short*)(ws + 43057152);   //    524,288 B
    unsigned short* W2t    = (unsigned short*)(ws + 43581440);   //    131,072 B

    prep_weights<<<dim3(3456), dim3(256), 0, stream>>>(enc_W, z_W, W1, W2,
                                                       enc_Wt, z_Wt, W1t, W2t);
    gemm1<<<dim3(512), dim3(256), 0, stream>>>(X, enc_Wt, enc_b, hb);
    gemm2<<<dim3(512), dim3(256), 0, stream>>>(hb, z_Wt, z_b, z);
    expert_kernel<<<dim3(256), dim3(256), 0, stream>>>(z, mu, W1t, b1, W2t, b2, out);
}